// Round 11
// baseline (71.879 us; speedup 1.0000x reference)
//
#include <hip/hip_runtime.h>
#include <math.h>

#define BATCH 8
#define CIN 64
#define COUT 64
#define HH 128
#define WW 128
#define HW (HH*WW)
#define TPX 64       // pixels per block = 2 rows x 32 cols
#define KDIM 576
#define NR 6         // staged rows  (h-2 .. h+3, clamped)
#define NC 38        // staged cols  (w0-2 .. w0+35, clamped)
#define NSLOT (NR*NC)          // 228 col-slots
#define NITEM (NSLOT*8)        // 1824 16B-chunks

typedef __attribute__((ext_vector_type(8))) short short8;
typedef __attribute__((ext_vector_type(4))) float f32x4;
typedef _Float16 h2   __attribute__((ext_vector_type(2)));
typedef _Float16 h8   __attribute__((ext_vector_type(8)));

__device__ __forceinline__ short f2h(float f) {
    union { _Float16 h; short s; } u;
    u.h = (_Float16)f;
    return u.s;
}

// ---------------- Kernel 1: x[b][c][h][w] fp32 -> xT[b][h][w][c] fp16 ----------------
__global__ void __launch_bounds__(256) xpose_kernel(const float* __restrict__ x,
                                                    unsigned short* __restrict__ xT) {
    int idx = blockIdx.x * 256 + threadIdx.x;   // 1,048,576 total
    int c8 = idx & 7;
    int w  = (idx >> 3) & 127;
    int h  = (idx >> 10) & 127;
    int b  = idx >> 17;
    const float* xp = x + (((size_t)(b * 64 + c8 * 8) * 128 + h) * 128 + w);
    short8 o;
#pragma unroll
    for (int j = 0; j < 8; ++j)
        o[j] = f2h(xp[(size_t)j * HW]);
    *(short8*)(xT + (size_t)idx * 8) = o;
}

// ---------------- Kernel 2: weights -> MFMA-fragment order, fp16 ----------------
// wt2   : 72 frags [(kf*2+s)*4+m][lane][8]   (main conv weights)
// wtoff2: 36 frags [kk*2+m][lane][8]         (offset conv weights, rows>=27 zero)
__global__ void __launch_bounds__(256) wcast_kernel(const float* __restrict__ w_dcn,
                                                    const float* __restrict__ w_off,
                                                    unsigned short* __restrict__ wt2,
                                                    unsigned short* __restrict__ wtoff2) {
    int gid = blockIdx.x * 256 + threadIdx.x;
    if (gid < 72 * 64) {
        int frag = gid >> 6, lane = gid & 63;
        int kf = frag >> 3, s = (frag >> 2) & 1, m = frag & 3;
        int o = m * 16 + (lane & 15);
        int cb = s * 32 + (lane >> 4) * 8;
        short8 v;
#pragma unroll
        for (int j = 0; j < 8; ++j)
            v[j] = f2h(w_dcn[(o * 64 + cb + j) * 9 + kf]);
        *(short8*)(wt2 + (size_t)gid * 8) = v;
    } else {
        int g2 = gid - 72 * 64;
        if (g2 < 36 * 64) {
            int frag = g2 >> 6, lane = g2 & 63;
            int kk = frag >> 1, m = frag & 1;
            int kf = kk >> 1;
            int o = m * 16 + (lane & 15);
            int cb = (kk & 1) * 32 + (lane >> 4) * 8;
            short8 v;
#pragma unroll
            for (int j = 0; j < 8; ++j)
                v[j] = (o < 27) ? f2h(w_off[(o * 64 + cb + j) * 9 + kf]) : (short)0;
            *(short8*)(wtoff2 + (size_t)g2 * 8) = v;
        }
    }
}

// ---------------- Kernel 3: fused, 2x32 tile, LDS x-window + packed-f16 interp ----------------
__global__ void __launch_bounds__(256, 4) fused_dcn_kernel(
        const unsigned short* __restrict__ xT,
        const unsigned short* __restrict__ wtoff2,
        const float* __restrict__ b_off,
        const unsigned short* __restrict__ wt2,
        float* __restrict__ out) {
    __shared__ char  s_x[NSLOT * 128];          // 29,184 B  [slot][chunk ^ (c&7) ^ r]
    __shared__ float s_om[TPX * 29];            // 7,424 B   -> total 36,608 B, 4 blk/CU

    int t = threadIdx.x;
    int blk0 = blockIdx.x;
    int blk = (blk0 & 7) * 256 + (blk0 >> 3);   // XCD swizzle (2048 = 8*256, bijective)
    int b = blk >> 8;
    int rem = blk & 255;
    int h = (rem >> 2) << 1;                    // tile rows h, h+1
    int w0 = (rem & 3) << 5;                    // tile cols w0..w0+31

    int lane = t & 63;
    int wv = t >> 6;
    int l15 = lane & 15;
    int g4 = lane >> 4;
    int pxl = wv * 16 + l15;                    // local pixel 0..63
    int pr = pxl >> 5;                          // 0/1 tile row
    int pc = pxl & 31;                          // tile col
    int hh = h + pr;                            // global row
    int wg = w0 + pc;                           // global col

    const unsigned short* xTb = xT + (size_t)b * HW * 64;

    // ---- phase 0: stage x window into LDS (issue-early / write-late) ----
    {
        short8 v[8];
        int cs[8], cl[8];
#pragma unroll
        for (int it = 0; it < 8; ++it) {
            int i = it * 256 + t;
            if (i < NITEM) {
                int c_slot = i >> 3;
                cl[it] = i & 7;
                int r5 = c_slot / NC;
                int c  = c_slot - r5 * NC;
                cs[it] = c_slot;
                int row_src = min(max(h - 2 + r5, 0), 127);
                int col_src = min(max(w0 - 2 + c, 0), 127);
                v[it] = *(const short8*)(xTb + ((size_t)row_src * 128 + col_src) * 64 + cl[it] * 8);
            }
        }
#pragma unroll
        for (int it = 0; it < 8; ++it) {
            int i = it * 256 + t;
            if (i < NITEM) {
                int c_slot = cs[it];
                int r5 = c_slot / NC;
                int c = c_slot - r5 * NC;
                int baddr = c_slot * 128 + ((cl[it] ^ (c & 7) ^ r5) << 4);
                *(short8*)(s_x + baddr) = v[it];
            }
        }
    }
    __syncthreads();

    // ---- phase A: offset conv (27ch) via f16 MFMA, x from LDS, coalesced A ----
    {
        f32x4 ca0 = {0.f, 0.f, 0.f, 0.f};
        f32x4 ca1 = {0.f, 0.f, 0.f, 0.f};
#pragma unroll
        for (int kk = 0; kk < 18; ++kk) {
            int kf = kk >> 1;
            int ky = kf / 3, kx = kf % 3;
            int cq = (kk & 1) * 4 + g4;
            int row = hh - 1 + ky;
            int col = wg - 1 + kx;
            int wr = pr + 1 + ky;               // window row 1..5
            int cc = pc + 1 + kx;               // window col 1..34
            int addr = (wr * NC + cc) * 128 + ((cq ^ (cc & 7) ^ wr) << 4);
            h8 bfrag = *(const h8*)(s_x + addr);
            if (!((unsigned)row < 128u && (unsigned)col < 128u))
                bfrag = (h8){0, 0, 0, 0, 0, 0, 0, 0};
            h8 a0 = *(const h8*)(wtoff2 + (size_t)(kk * 2 + 0) * 512 + lane * 8);
            h8 a1 = *(const h8*)(wtoff2 + (size_t)(kk * 2 + 1) * 512 + lane * 8);
            ca0 = __builtin_amdgcn_mfma_f32_16x16x32_f16(a0, bfrag, ca0, 0, 0, 0);
            ca1 = __builtin_amdgcn_mfma_f32_16x16x32_f16(a1, bfrag, ca1, 0, 0, 0);
        }
        int ch0 = g4 * 4;
#pragma unroll
        for (int r = 0; r < 4; ++r) {
            s_om[pxl * 29 + ch0 + r] = ca0[r] + b_off[ch0 + r];
            if (ch0 + 16 + r < 27)
                s_om[pxl * 29 + 16 + ch0 + r] = ca1[r] + b_off[16 + ch0 + r];
        }
    }
    __syncthreads();

    // ---- main loop: packed-f16 interp, software-pipelined A-frags ----
    f32x4 acc0 = {0.f, 0.f, 0.f, 0.f};
    f32x4 acc1 = {0.f, 0.f, 0.f, 0.f};
    f32x4 acc2 = {0.f, 0.f, 0.f, 0.f};
    f32x4 acc3 = {0.f, 0.f, 0.f, 0.f};
    const float* omb = s_om + pxl * 29;

    h8 a_cur[8], a_nxt[8];
#pragma unroll
    for (int q = 0; q < 8; ++q)
        a_cur[q] = *(const h8*)(wt2 + (size_t)q * 512 + lane * 8);

#pragma unroll
    for (int kf = 0; kf < 9; ++kf) {
        if (kf < 8) {
#pragma unroll
            for (int q = 0; q < 8; ++q)
                a_nxt[q] = *(const h8*)(wt2 + (size_t)((kf + 1) * 8 + q) * 512 + lane * 8);
        }

        float dy = omb[2 * kf], dx = omb[2 * kf + 1];
        float mr = omb[18 + kf];
        float m = 1.0f / (1.0f + __expf(-mr));
        float py  = (float)(hh - 1 + kf / 3) + dy;
        float pxf = (float)(wg - 1 + kf % 3) + dx;
        float y0f = floorf(py), x0f = floorf(pxf);
        float wy1 = py - y0f, wx1 = pxf - x0f;
        float wy0 = 1.f - wy1, wx0 = 1.f - wx1;
        int y0 = (int)y0f, x0 = (int)x0f;
        float my0 = ((unsigned)y0 < 128u) ? m : 0.f;
        float my1 = ((unsigned)(y0 + 1) < 128u) ? m : 0.f;
        float vx0 = ((unsigned)x0 < 128u) ? 1.f : 0.f;
        float vx1 = ((unsigned)(x0 + 1) < 128u) ? 1.f : 0.f;
        float w00 = wy0 * wx0 * my0 * vx0, w01 = wy0 * wx1 * my0 * vx1;
        float w10 = wy1 * wx0 * my1 * vx0, w11 = wy1 * wx1 * my1 * vx1;

        _Float16 h00 = (_Float16)w00, h01 = (_Float16)w01;
        _Float16 h10 = (_Float16)w10, h11 = (_Float16)w11;
        h2 W00 = {h00, h00}, W01 = {h01, h01}, W10 = {h10, h10}, W11 = {h11, h11};

        int r50 = y0 - (h - 2);                 // window row of top corners (0..4 valid)
        int c0  = x0 - (w0 - 2);                // window col of left corners (0..36 valid)
        bool inw = (r50 >= 0) && (r50 <= 4) && (c0 >= 0) && (c0 <= 36);
        int a00 = (r50 * NC + c0) * 128;
        int a01 = a00 + 128;
        int a10 = a00 + NC * 128;
        int a11 = a10 + 128;
        int sw00 = (((c0 & 7) ^ (r50 & 7)) << 4);
        int sw01 = ((((c0 + 1) & 7) ^ (r50 & 7)) << 4);
        int sw10 = (((c0 & 7) ^ ((r50 + 1) & 7)) << 4);
        int sw11 = ((((c0 + 1) & 7) ^ ((r50 + 1) & 7)) << 4);

#pragma unroll
        for (int s = 0; s < 2; ++s) {
            int q4 = (s * 4 + g4) << 4;
            h8 v00, v01, v10, v11;
            if (inw) {
                v00 = *(const h8*)(s_x + a00 + (q4 ^ sw00));
                v01 = *(const h8*)(s_x + a01 + (q4 ^ sw01));
                v10 = *(const h8*)(s_x + a10 + (q4 ^ sw10));
                v11 = *(const h8*)(s_x + a11 + (q4 ^ sw11));
            } else {                            // rare: sample outside staged window
                int cb = s * 32 + g4 * 8;
                int y0c = min(max(y0, 0), 127) * 8192;
                int y1c = min(max(y0 + 1, 0), 127) * 8192;
                int x0c = min(max(x0, 0), 127) * 64;
                int x1c = min(max(x0 + 1, 0), 127) * 64;
                v00 = *(const h8*)(xTb + y0c + x0c + cb);
                v01 = *(const h8*)(xTb + y0c + x1c + cb);
                v10 = *(const h8*)(xTb + y1c + x0c + cb);
                v11 = *(const h8*)(xTb + y1c + x1c + cb);
            }
            h8 bfrag;
            const h2* p00 = (const h2*)&v00;
            const h2* p01 = (const h2*)&v01;
            const h2* p10 = (const h2*)&v10;
            const h2* p11 = (const h2*)&v11;
            h2* bp = (h2*)&bfrag;
#pragma unroll
            for (int j = 0; j < 4; ++j) {
                h2 r = p11[j] * W11;
                r = p10[j] * W10 + r;
                r = p01[j] * W01 + r;
                r = p00[j] * W00 + r;
                bp[j] = r;
            }
            acc0 = __builtin_amdgcn_mfma_f32_16x16x32_f16(a_cur[s * 4 + 0], bfrag, acc0, 0, 0, 0);
            acc1 = __builtin_amdgcn_mfma_f32_16x16x32_f16(a_cur[s * 4 + 1], bfrag, acc1, 0, 0, 0);
            acc2 = __builtin_amdgcn_mfma_f32_16x16x32_f16(a_cur[s * 4 + 2], bfrag, acc2, 0, 0, 0);
            acc3 = __builtin_amdgcn_mfma_f32_16x16x32_f16(a_cur[s * 4 + 3], bfrag, acc3, 0, 0, 0);
        }
#pragma unroll
        for (int q = 0; q < 8; ++q)
            a_cur[q] = a_nxt[q];
    }

    // ---- store ----
    float* obp = out + (size_t)b * COUT * HW + (size_t)hh * WW + wg;
    int or0 = g4 * 4;
#pragma unroll
    for (int r = 0; r < 4; ++r) {
        obp[(size_t)(or0 + r) * HW]      = acc0[r];
        obp[(size_t)(16 + or0 + r) * HW] = acc1[r];
        obp[(size_t)(32 + or0 + r) * HW] = acc2[r];
        obp[(size_t)(48 + or0 + r) * HW] = acc3[r];
    }
}

extern "C" void kernel_launch(void* const* d_in, const int* in_sizes, int n_in,
                              void* d_out, int out_size, void* d_ws, size_t ws_size,
                              hipStream_t stream) {
    (void)in_sizes; (void)n_in; (void)out_size; (void)ws_size;
    const float* x        = (const float*)d_in[0];
    const float* w_offset = (const float*)d_in[1];
    const float* b_offset = (const float*)d_in[2];
    const float* w_dcn    = (const float*)d_in[3];
    float* out = (float*)d_out;

    unsigned short* xT     = (unsigned short*)d_ws;                      // 16,777,216 B
    unsigned short* wt2    = (unsigned short*)((char*)d_ws + 16777216);  // 73,728 B
    unsigned short* wtoff2 = (unsigned short*)((char*)d_ws + 16850944);  // 36,864 B

    xpose_kernel<<<4096, 256, 0, stream>>>(x, xT);
    wcast_kernel<<<27, 256, 0, stream>>>(w_dcn, w_offset, wt2, wtoff2);
    fused_dcn_kernel<<<2048, 256, 0, stream>>>(xT, wtoff2, b_offset, wt2, out);
}

// Round 12
// 61.927 us; speedup vs baseline: 1.1607x; 1.1607x over previous
//
#include <hip/hip_runtime.h>
#include <math.h>

#define BATCH 8
#define CIN 64
#define COUT 64
#define HH 128
#define WW 128
#define HW (HH*WW)
#define TPX 64       // pixels per block (half row)
#define KDIM 576
#define NR 5         // staged rows  (h-2 .. h+2, clamped)
#define NC 69        // staged cols  (w0-2 .. w0+66, clamped)
#define NSLOT (NR*NC)          // 345 col-slots
#define NITEM (NSLOT*8)        // 2760 16B-chunks

typedef __attribute__((ext_vector_type(8))) short short8;
typedef __attribute__((ext_vector_type(4))) float f32x4;
typedef _Float16 h2   __attribute__((ext_vector_type(2)));
typedef _Float16 h8   __attribute__((ext_vector_type(8)));

__device__ __forceinline__ short f2h(float f) {
    union { _Float16 h; short s; } u;
    u.h = (_Float16)f;
    return u.s;
}

// ---------------- Kernel 1: transpose + weight reorder (merged) ----------------
// blocks 0..4095 : x[b][c][h][w] fp32 -> xT[b][h][w][c] fp16
// blocks 4096+   : weights -> MFMA-fragment order fp16
__global__ void __launch_bounds__(256) prep_kernel(const float* __restrict__ x,
                                                   unsigned short* __restrict__ xT,
                                                   const float* __restrict__ w_dcn,
                                                   const float* __restrict__ w_off,
                                                   unsigned short* __restrict__ wt2,
                                                   unsigned short* __restrict__ wtoff2) {
    if (blockIdx.x < 4096) {
        int idx = blockIdx.x * 256 + threadIdx.x;   // 1,048,576 total
        int c8 = idx & 7;
        int w  = (idx >> 3) & 127;
        int h  = (idx >> 10) & 127;
        int b  = idx >> 17;
        const float* xp = x + (((size_t)(b * 64 + c8 * 8) * 128 + h) * 128 + w);
        short8 o;
#pragma unroll
        for (int j = 0; j < 8; ++j)
            o[j] = f2h(xp[(size_t)j * HW]);
        *(short8*)(xT + (size_t)idx * 8) = o;
        return;
    }
    int gid = (blockIdx.x - 4096) * 256 + threadIdx.x;
    if (gid < 72 * 64) {
        int frag = gid >> 6, lane = gid & 63;
        int kf = frag >> 3, s = (frag >> 2) & 1, m = frag & 3;
        int o = m * 16 + (lane & 15);
        int cb = s * 32 + (lane >> 4) * 8;
        short8 v;
#pragma unroll
        for (int j = 0; j < 8; ++j)
            v[j] = f2h(w_dcn[(o * 64 + cb + j) * 9 + kf]);
        *(short8*)(wt2 + (size_t)gid * 8) = v;
    } else {
        int g2 = gid - 72 * 64;
        if (g2 < 36 * 64) {
            int frag = g2 >> 6, lane = g2 & 63;
            int kk = frag >> 1, m = frag & 1;
            int kf = kk >> 1;
            int o = m * 16 + (lane & 15);
            int cb = (kk & 1) * 32 + (lane >> 4) * 8;
            short8 v;
#pragma unroll
            for (int j = 0; j < 8; ++j)
                v[j] = (o < 27) ? f2h(w_off[(o * 64 + cb + j) * 9 + kf]) : (short)0;
            *(short8*)(wtoff2 + (size_t)g2 * 8) = v;
        }
    }
}

// ---------------- Kernel 2: fused, LDS x-tile + packed-f16 interp -> MFMA ----------------
__global__ void __launch_bounds__(256, 3) fused_dcn_kernel(
        const unsigned short* __restrict__ xT,
        const unsigned short* __restrict__ wtoff2,
        const float* __restrict__ b_off,
        const unsigned short* __restrict__ wt2,
        float* __restrict__ out) {
    __shared__ char  s_x[NSLOT * 128];          // 44,160 B  [slot][chunk ^ (c&7) ^ r5]
    __shared__ float s_geo[TPX * 36];           // 9,216 B: [px][kf]{dy,dx,m,pad}

    int t = threadIdx.x;
    int blk0 = blockIdx.x;
    int blk = (blk0 & 7) * 256 + (blk0 >> 3);   // XCD swizzle (2048 = 8*256, bijective)
    int b = blk >> 8;
    int rem = blk & 255;
    int h = rem >> 1;                            // tile = 64 px of one row
    int w0 = (rem & 1) << 6;

    int lane = t & 63;
    int wv = t >> 6;
    int l15 = lane & 15;
    int g4 = lane >> 4;
    int pxl = wv * 16 + l15;                    // local pixel 0..63
    int wg = w0 + pxl;                          // global col

    const unsigned short* xTb = xT + (size_t)b * HW * 64;

    // ---- phase 0: stage x window into LDS (issue-early / write-late) ----
    {
        short8 v[11];
        int cs[11], cl[11];
#pragma unroll
        for (int it = 0; it < 11; ++it) {
            int i = it * 256 + t;
            if (i < NITEM) {
                int c_slot = i >> 3;
                cl[it] = i & 7;
                int r5 = c_slot / NC;
                int c  = c_slot - r5 * NC;
                cs[it] = c_slot;
                int row_src = min(max(h - 2 + r5, 0), 127);
                int col_src = min(max(w0 - 2 + c, 0), 127);
                v[it] = *(const short8*)(xTb + ((size_t)row_src * 128 + col_src) * 64 + cl[it] * 8);
            }
        }
#pragma unroll
        for (int it = 0; it < 11; ++it) {
            int i = it * 256 + t;
            if (i < NITEM) {
                int c_slot = cs[it];
                int r5 = c_slot / NC;
                int c = c_slot - r5 * NC;
                int baddr = c_slot * 128 + ((cl[it] ^ (c & 7) ^ r5) << 4);
                *(short8*)(s_x + baddr) = v[it];
            }
        }
    }
    __syncthreads();

    // ---- phase A: offset conv (27ch) via f16 MFMA; write packed geo {dy,dx,sig(m)} ----
    {
        f32x4 ca0 = {0.f, 0.f, 0.f, 0.f};
        f32x4 ca1 = {0.f, 0.f, 0.f, 0.f};
#pragma unroll
        for (int kk = 0; kk < 18; ++kk) {
            int kf = kk >> 1;
            int ky = kf / 3, kx = kf % 3;
            int cq = (kk & 1) * 4 + g4;
            int row = h - 1 + ky;
            int col = wg - 1 + kx;
            int cc = pxl + 1 + kx;              // window col index
            int wr = ky + 1;                    // window row 1..3
            int addr = (wr * NC + cc) * 128 + ((cq ^ (cc & 7) ^ wr) << 4);
            h8 bfrag = *(const h8*)(s_x + addr);
            if (!((unsigned)row < 128u && (unsigned)col < 128u))
                bfrag = (h8){0, 0, 0, 0, 0, 0, 0, 0};
            h8 a0 = *(const h8*)(wtoff2 + (size_t)(kk * 2 + 0) * 512 + lane * 8);
            h8 a1 = *(const h8*)(wtoff2 + (size_t)(kk * 2 + 1) * 512 + lane * 8);
            ca0 = __builtin_amdgcn_mfma_f32_16x16x32_f16(a0, bfrag, ca0, 0, 0, 0);
            ca1 = __builtin_amdgcn_mfma_f32_16x16x32_f16(a1, bfrag, ca1, 0, 0, 0);
        }
        // scatter into s_geo[px][kf]{0:dy,1:dx,2:m}
        float* gp = s_geo + pxl * 36;
        int ch0 = g4 * 4;
#pragma unroll
        for (int r = 0; r < 4; ++r) {
            int ch = ch0 + r;                   // 0..15 -> dy/dx of kf 0..7
            float v1 = ca0[r] + b_off[ch];
            gp[(ch >> 1) * 4 + (ch & 1)] = v1;
            int ch2 = 16 + ch;                  // 16..31
            if (ch2 < 18) {                     // dy8 / dx8
                float v2 = ca1[r] + b_off[ch2];
                gp[8 * 4 + (ch2 - 16)] = v2;
            } else if (ch2 < 27) {              // mask 0..8 -> sigmoid here
                float v2 = ca1[r] + b_off[ch2];
                gp[(ch2 - 18) * 4 + 2] = 1.0f / (1.0f + __expf(-v2));
            }
        }
    }
    __syncthreads();

    // ---- main loop: packed-f16 interp, software-pipelined A-frags ----
    f32x4 acc0 = {0.f, 0.f, 0.f, 0.f};
    f32x4 acc1 = {0.f, 0.f, 0.f, 0.f};
    f32x4 acc2 = {0.f, 0.f, 0.f, 0.f};
    f32x4 acc3 = {0.f, 0.f, 0.f, 0.f};
    const f32x4* geo = (const f32x4*)(s_geo + pxl * 36);

    h8 a_cur[8], a_nxt[8];
#pragma unroll
    for (int q = 0; q < 8; ++q)
        a_cur[q] = *(const h8*)(wt2 + (size_t)q * 512 + lane * 8);

#pragma unroll
    for (int kf = 0; kf < 9; ++kf) {
        if (kf < 8) {
#pragma unroll
            for (int q = 0; q < 8; ++q)
                a_nxt[q] = *(const h8*)(wt2 + (size_t)((kf + 1) * 8 + q) * 512 + lane * 8);
        }

        f32x4 g = geo[kf];
        float dy = g[0], dx = g[1], m = g[2];
        float py  = (float)(h - 1 + kf / 3) + dy;
        float pxf = (float)(wg - 1 + kf % 3) + dx;
        float y0f = floorf(py), x0f = floorf(pxf);
        float wy1 = py - y0f, wx1 = pxf - x0f;
        float wy0 = 1.f - wy1, wx0 = 1.f - wx1;
        int y0 = (int)y0f, x0 = (int)x0f;
        float ay0 = ((unsigned)y0 < 128u) ? wy0 * m : 0.f;
        float ay1 = ((unsigned)(y0 + 1) < 128u) ? wy1 * m : 0.f;
        float ax0 = ((unsigned)x0 < 128u) ? wx0 : 0.f;
        float ax1 = ((unsigned)(x0 + 1) < 128u) ? wx1 : 0.f;
        float w00 = ay0 * ax0, w01 = ay0 * ax1;
        float w10 = ay1 * ax0, w11 = ay1 * ax1;

        _Float16 h00 = (_Float16)w00, h01 = (_Float16)w01;
        _Float16 h10 = (_Float16)w10, h11 = (_Float16)w11;
        h2 W00 = {h00, h00}, W01 = {h01, h01}, W10 = {h10, h10}, W11 = {h11, h11};

        int r50 = y0 - (h - 2);                 // window row of top corners
        int c0  = x0 - (w0 - 2);                // window col of left corners
        bool inw = (r50 >= 0) && (r50 <= 3) && (c0 >= 0) && (c0 <= 67);
        int a00 = (r50 * NC + c0) * 128;
        int a01 = a00 + 128;
        int a10 = a00 + NC * 128;
        int a11 = a10 + 128;
        int sw00 = (((c0 & 7) ^ (r50 & 7)) << 4);
        int sw01 = ((((c0 + 1) & 7) ^ (r50 & 7)) << 4);
        int sw10 = (((c0 & 7) ^ ((r50 + 1) & 7)) << 4);
        int sw11 = ((((c0 + 1) & 7) ^ ((r50 + 1) & 7)) << 4);

#pragma unroll
        for (int s = 0; s < 2; ++s) {
            int q4 = (s * 4 + g4) << 4;
            h8 v00, v01, v10, v11;
            if (inw) {
                v00 = *(const h8*)(s_x + a00 + (q4 ^ sw00));
                v01 = *(const h8*)(s_x + a01 + (q4 ^ sw01));
                v10 = *(const h8*)(s_x + a10 + (q4 ^ sw10));
                v11 = *(const h8*)(s_x + a11 + (q4 ^ sw11));
            } else {                            // rare: sample outside staged window
                int cb = s * 32 + g4 * 8;
                int y0c = min(max(y0, 0), 127) * 8192;
                int y1c = min(max(y0 + 1, 0), 127) * 8192;
                int x0c = min(max(x0, 0), 127) * 64;
                int x1c = min(max(x0 + 1, 0), 127) * 64;
                v00 = *(const h8*)(xTb + y0c + x0c + cb);
                v01 = *(const h8*)(xTb + y0c + x1c + cb);
                v10 = *(const h8*)(xTb + y1c + x0c + cb);
                v11 = *(const h8*)(xTb + y1c + x1c + cb);
            }
            h8 bfrag;
            const h2* p00 = (const h2*)&v00;
            const h2* p01 = (const h2*)&v01;
            const h2* p10 = (const h2*)&v10;
            const h2* p11 = (const h2*)&v11;
            h2* bp = (h2*)&bfrag;
#pragma unroll
            for (int j = 0; j < 4; ++j) {
                h2 r = p11[j] * W11;
                r = p10[j] * W10 + r;
                r = p01[j] * W01 + r;
                r = p00[j] * W00 + r;
                bp[j] = r;
            }
            acc0 = __builtin_amdgcn_mfma_f32_16x16x32_f16(a_cur[s * 4 + 0], bfrag, acc0, 0, 0, 0);
            acc1 = __builtin_amdgcn_mfma_f32_16x16x32_f16(a_cur[s * 4 + 1], bfrag, acc1, 0, 0, 0);
            acc2 = __builtin_amdgcn_mfma_f32_16x16x32_f16(a_cur[s * 4 + 2], bfrag, acc2, 0, 0, 0);
            acc3 = __builtin_amdgcn_mfma_f32_16x16x32_f16(a_cur[s * 4 + 3], bfrag, acc3, 0, 0, 0);
        }
#pragma unroll
        for (int q = 0; q < 8; ++q)
            a_cur[q] = a_nxt[q];
    }

    // ---- store ----
    float* obp = out + (size_t)b * COUT * HW + (size_t)h * WW + wg;
    int or0 = g4 * 4;
#pragma unroll
    for (int r = 0; r < 4; ++r) {
        obp[(size_t)(or0 + r) * HW]      = acc0[r];
        obp[(size_t)(16 + or0 + r) * HW] = acc1[r];
        obp[(size_t)(32 + or0 + r) * HW] = acc2[r];
        obp[(size_t)(48 + or0 + r) * HW] = acc3[r];
    }
}

extern "C" void kernel_launch(void* const* d_in, const int* in_sizes, int n_in,
                              void* d_out, int out_size, void* d_ws, size_t ws_size,
                              hipStream_t stream) {
    (void)in_sizes; (void)n_in; (void)out_size; (void)ws_size;
    const float* x        = (const float*)d_in[0];
    const float* w_offset = (const float*)d_in[1];
    const float* b_offset = (const float*)d_in[2];
    const float* w_dcn    = (const float*)d_in[3];
    float* out = (float*)d_out;

    unsigned short* xT     = (unsigned short*)d_ws;                      // 16,777,216 B
    unsigned short* wt2    = (unsigned short*)((char*)d_ws + 16777216);  // 73,728 B
    unsigned short* wtoff2 = (unsigned short*)((char*)d_ws + 16850944);  // 36,864 B

    prep_kernel<<<4096 + 27, 256, 0, stream>>>(x, xT, w_dcn, w_offset, wt2, wtoff2);
    fused_dcn_kernel<<<2048, 256, 0, stream>>>(xT, wtoff2, b_offset, wt2, out);
}